// Round 3
// baseline (3249.589 us; speedup 1.0000x reference)
//
#include <hip/hip_runtime.h>
#include <hip/hip_bf16.h>
#include <cstdint>
#include <cstddef>

using bf16 = __hip_bfloat16;

typedef __attribute__((ext_vector_type(8))) short s8vec;    // 8 x bf16 (4 VGPRs) MFMA frag
typedef __attribute__((ext_vector_type(4))) float f4vec;    // 4 x fp32 accumulator

// Problem dims
#define SD 4096
#define TD 64
#define ID 64
#define EHD 128
#define ED 256
#define HD 512
#define GD 2048   // 4*H
#define OD 128
#define F1D 256
#define F2D 64

__device__ __forceinline__ float sigmf(float x) { return 1.0f / (1.0f + __expf(-x)); }
__device__ __forceinline__ float tanh_fast(float x) { return 1.0f - 2.0f / (__expf(2.0f * x) + 1.0f); }

__device__ __forceinline__ void async16(const bf16* g, void* lds) {
    __builtin_amdgcn_global_load_lds(
        (const __attribute__((address_space(1))) void*)g,
        (__attribute__((address_space(3))) void*)lds, 16, 0, 0);
}

// ---------------------------------------------------------------------------
// dtype detection: scan inputData interpreted as bf16; fp32 data shows
// all-ones exponents (NaN/Inf bit patterns) in mantissa low-halves.
// ---------------------------------------------------------------------------
__global__ void detect_kernel(const unsigned short* __restrict__ data,
                              int* __restrict__ flag)
{
    __shared__ int found;
    if (threadIdx.x == 0) found = 0;
    __syncthreads();
    int loc = 0;
    for (int i = threadIdx.x; i < 65536; i += 256) {
        unsigned short u = data[i];
        if ((u & 0x7F80u) == 0x7F80u) loc = 1;
    }
    if (loc) found = 1;   // benign race, all writers store 1
    __syncthreads();
    if (threadIdx.x == 0) flag[0] = found;   // 1 = fp32 inputs, 0 = bf16
}

// canonicalize one tensor to bf16 (src is fp32 if *flag else bf16)
__global__ void cvt_kernel(const void* __restrict__ src, bf16* __restrict__ dst,
                           int n, const int* __restrict__ flag)
{
    int idx = blockIdx.x * 256 + threadIdx.x;
    if (idx >= n) return;
    if (flag[0])
        dst[idx] = __float2bfloat16(((const float*)src)[idx]);
    else
        dst[idx] = ((const bf16*)src)[idx];
}

// ---------------------------------------------------------------------------
// Generic NT GEMM: C[m,n] = act( scale * sum_k A[m,k]*B[n,k] + bias[n] )
// A split in K: rows come from A1 (k < ksplit, lda1) then A2 (lda2).
// B is [N,K] row-major bf16. M%128==0, K%64==0. grid = (M/128, N/128).
// 256 threads = 4 waves, each wave owns a 64x64 quadrant.  (m97 structure)
// ---------------------------------------------------------------------------
constexpr int MODE_BF16 = 0;     // bf16 store at Cp[row*ldc+col], masked col<ncols
constexpr int MODE_F32 = 1;      // fp32 store
constexpr int MODE_SCATTER = 2;  // bf16 store, row r=(s*64+t) -> t*4096+s

template <int MODE>
__global__ __launch_bounds__(256, 2)
void gemm_kernel(const bf16* __restrict__ A1, int lda1,
                 const bf16* __restrict__ A2, int lda2, int ksplit,
                 const bf16* __restrict__ B, int ldb,
                 const float* __restrict__ bias,
                 const float* __restrict__ scale,
                 int relu, void* __restrict__ Cp, int ldc,
                 int K, int ncols)
{
    __shared__ __align__(16) bf16 As[128 * 64];
    __shared__ __align__(16) bf16 Bs[128 * 64];

    const int tid = threadIdx.x;
    const int lane = tid & 63;
    const int w = tid >> 6;
    const int wm = w & 1, wn = w >> 1;
    const int m0 = blockIdx.x * 128, n0 = blockIdx.y * 128;
    const int lm = lane & 15, lq = lane >> 4;

    f4vec acc[4][4];
#pragma unroll
    for (int i = 0; i < 4; ++i)
#pragma unroll
        for (int j = 0; j < 4; ++j) acc[i][j] = (f4vec){0.f, 0.f, 0.f, 0.f};

    for (int kc = 0; kc < K; kc += 64) {
        const bf16* Ab;
        int Alda, kk;
        if (kc < ksplit) { Ab = A1; Alda = lda1; kk = kc; }
        else             { Ab = A2; Alda = lda2; kk = kc - ksplit; }

        // Stage A and B tiles: 128 rows x 64 cols bf16 = 16KB each.
        // LDS dest = wave-uniform base + lane*16 (global_load_lds semantics).
#pragma unroll
        for (int it = 0; it < 4; ++it) {
            int flat = it * 256 + tid;
            int row = flat >> 3, colu = flat & 7;
            const bf16* ga = Ab + (size_t)(m0 + row) * Alda + kk + colu * 8;
            const bf16* gb = B + (size_t)(n0 + row) * ldb + kc + colu * 8;
            uint32_t off = (uint32_t)(it * 256 + (tid & ~63)) * 16u;
            async16(ga, (char*)As + off);
            async16(gb, (char*)Bs + off);
        }
        __syncthreads();

#pragma unroll
        for (int ks = 0; ks < 64; ks += 32) {
            s8vec af[4], bfr[4];
#pragma unroll
            for (int mi = 0; mi < 4; ++mi)
                af[mi] = *(const s8vec*)(As + (wm * 64 + mi * 16 + lm) * 64 + ks + lq * 8);
#pragma unroll
            for (int ni = 0; ni < 4; ++ni)
                bfr[ni] = *(const s8vec*)(Bs + (wn * 64 + ni * 16 + lm) * 64 + ks + lq * 8);
#pragma unroll
            for (int mi = 0; mi < 4; ++mi)
#pragma unroll
                for (int ni = 0; ni < 4; ++ni)
                    acc[mi][ni] = __builtin_amdgcn_mfma_f32_16x16x32_bf16(af[mi], bfr[ni], acc[mi][ni], 0, 0, 0);
        }
        __syncthreads();
    }

    const float sc = scale ? scale[0] : 1.0f;
#pragma unroll
    for (int mi = 0; mi < 4; ++mi) {
#pragma unroll
        for (int ni = 0; ni < 4; ++ni) {
            const int gcol = n0 + wn * 64 + ni * 16 + lm;
            const float bv = bias[gcol];
#pragma unroll
            for (int r = 0; r < 4; ++r) {
                const int grow = m0 + wm * 64 + mi * 16 + lq * 4 + r;
                float v = acc[mi][ni][r] * sc + bv;
                if (relu) v = fmaxf(v, 0.f);
                if constexpr (MODE == MODE_F32) {
                    ((float*)Cp)[(size_t)grow * ldc + gcol] = v;
                } else if constexpr (MODE == MODE_BF16) {
                    if (gcol < ncols)
                        ((bf16*)Cp)[(size_t)grow * ldc + gcol] = __float2bfloat16(v);
                } else {  // MODE_SCATTER: row = s*64+t -> dest row t*4096+s
                    const int crow = (grow & 63) * SD + (grow >> 6);
                    ((bf16*)Cp)[(size_t)crow * ldc + gcol] = __float2bfloat16(v);
                }
            }
        }
    }
}

// ---------------------------------------------------------------------------
// Small helper kernels (all consume canonical bf16 buffers)
// ---------------------------------------------------------------------------
__global__ void lane_kernel(const bf16* __restrict__ lane, const bf16* __restrict__ Wlg1,
                            const bf16* __restrict__ blg1, const bf16* __restrict__ Wlg2,
                            const bf16* __restrict__ blg2, float* __restrict__ laneC)
{
    if (threadIdx.x != 0) return;
    const float l = __bfloat162float(lane[0]);
    float acc = __bfloat162float(blg2[0]);
    for (int k = 0; k < 32; ++k) {
        float lg = fmaxf(l * __bfloat162float(Wlg1[k]) + __bfloat162float(blg1[k]), 0.f);
        acc += lg * __bfloat162float(Wlg2[k]);
    }
    float v = 1.f / (1.f + __expf(-acc));
    laneC[0] = v;
    laneC[1] = 1.f / v;
}

__global__ void zero_kernel(float* __restrict__ c0, bf16* __restrict__ h)
{
    int idx = blockIdx.x * 256 + threadIdx.x;
    if (idx < SD * HD) { c0[idx] = 0.f; h[idx] = __float2bfloat16(0.f); }
}

__global__ void pack_w_kernel(const bf16* __restrict__ Wih, const bf16* __restrict__ Whh,
                              bf16* __restrict__ Wp)
{
    int idx = blockIdx.x * 256 + threadIdx.x;
    if (idx >= GD * (ED + HD)) return;
    int n = idx / (ED + HD), k = idx % (ED + HD);
    Wp[idx] = (k < ED) ? Wih[(size_t)n * ED + k] : Whh[(size_t)n * HD + (k - ED)];
}

__global__ void bias_g_kernel(const bf16* __restrict__ bih, const bf16* __restrict__ bhh,
                              float* __restrict__ bg)
{
    int idx = blockIdx.x * 256 + threadIdx.x;
    if (idx < GD) bg[idx] = __bfloat162float(bih[idx]) + __bfloat162float(bhh[idx]);
}

__global__ void conv_bias_kernel(const bf16* __restrict__ src, float* __restrict__ dst,
                                 int n, int npad)
{
    int idx = blockIdx.x * 256 + threadIdx.x;
    if (idx < npad) dst[idx] = (idx < n) ? __bfloat162float(src[idx]) : 0.f;
}

__global__ void pad_wf2_kernel(const bf16* __restrict__ Wf2, bf16* __restrict__ Wp)
{
    int idx = blockIdx.x * 256 + threadIdx.x;  // 128 blocks x 256
    if (idx >= 128 * ED) return;
    int nrow = idx >> 8;
    Wp[idx] = (nrow < F2D) ? Wf2[idx] : __float2bfloat16(0.f);
}

// Fused gate nonlinearity + cell update + spatial maxpool(3,1,-inf pad).
// Recomputes h_pre for s-1 and s+1 redundantly (reads only c_in -> no race).
__global__ void gate_pool_kernel(const float* __restrict__ gates,
                                 const float* __restrict__ c_in,
                                 float* __restrict__ c_out,
                                 bf16* __restrict__ h_out)
{
    int idx = blockIdx.x * 256 + threadIdx.x;
    if (idx >= SD * HD) return;
    int s = idx >> 9, j = idx & (HD - 1);
    float hmax = -INFINITY, c_own = 0.f;
#pragma unroll
    for (int d = -1; d <= 1; ++d) {
        int ss = s + d;
        if (ss < 0 || ss >= SD) continue;
        const float* gr = gates + (size_t)ss * GD;
        float gi = gr[j], gf = gr[HD + j], gg = gr[2 * HD + j], go = gr[3 * HD + j];
        float cn = sigmf(gf) * c_in[(size_t)ss * HD + j] + sigmf(gi) * tanh_fast(gg);
        float hp = sigmf(go) * tanh_fast(cn);
        if (d == 0) c_own = cn;
        hmax = fmaxf(hmax, hp);
    }
    c_out[idx] = c_own;
    h_out[idx] = __float2bfloat16(hmax);
}

__global__ void f3_kernel(const bf16* __restrict__ xf2, const bf16* __restrict__ Wf3,
                          const bf16* __restrict__ bf3, const float* __restrict__ laneC,
                          void* __restrict__ out, const int* __restrict__ flag)
{
    int s = blockIdx.x * 256 + threadIdx.x;
    if (s >= SD) return;
    float acc = 0.f;
#pragma unroll
    for (int k = 0; k < F2D; ++k)
        acc += __bfloat162float(xf2[(size_t)s * F2D + k]) * __bfloat162float(Wf3[k]);
    float v = (acc + __bfloat162float(bf3[0])) * laneC[1];
    if (flag[0]) ((float*)out)[s] = v;
    else         ((bf16*)out)[s] = __float2bfloat16(v);
}

__global__ void finalize_kernel(const bf16* __restrict__ h, const float* __restrict__ c,
                                void* __restrict__ out, const int* __restrict__ flag)
{
    int idx = blockIdx.x * 256 + threadIdx.x;
    if (idx >= SD * HD) return;
    float hv = __bfloat162float(h[idx]);
    float cv = c[idx];
    if (flag[0]) {
        ((float*)out)[SD + idx] = hv;
        ((float*)out)[SD + SD * HD + idx] = cv;
    } else {
        ((bf16*)out)[SD + idx] = h[idx];
        ((bf16*)out)[SD + SD * HD + idx] = __float2bfloat16(cv);
    }
}

// ---------------------------------------------------------------------------
extern "C" void kernel_launch(void* const* d_in, const int* in_sizes, int n_in,
                              void* d_out, int out_size, void* d_ws, size_t ws_size,
                              hipStream_t stream)
{
    (void)in_sizes; (void)n_in; (void)out_size;

    char* wp = (char*)d_ws;
    auto carve = [&](size_t bytes) { char* p = wp; wp += (bytes + 255) & ~(size_t)255; return p; };

    // --- flag + canonical bf16 copies of all inputs (~37 MB) ---
    int* dflag = (int*)carve(sizeof(int));
    const int nelem[22] = {
        SD * TD * ID, 1, 32, 32, 32, 1,
        EHD * ID, EHD, ED * EHD, ED,
        GD * ED, GD, GD * HD, GD,
        OD * HD, OD, F1D * OD, F1D,
        F2D * F1D, F2D, F2D, 1
    };
    bf16* canon[22];
    for (int i = 0; i < 22; ++i) canon[i] = (bf16*)carve((size_t)nelem[i] * 2);

    const bf16* inputData = canon[0];
    const bf16* lane = canon[1];
    const bf16* Wlg1 = canon[2];  const bf16* blg1 = canon[3];
    const bf16* Wlg2 = canon[4];  const bf16* blg2 = canon[5];
    const bf16* We1 = canon[6];   const bf16* be1 = canon[7];
    const bf16* We2 = canon[8];   const bf16* be2 = canon[9];
    const bf16* Wih = canon[10];  const bf16* bih = canon[11];
    const bf16* Whh = canon[12];  const bf16* bhh = canon[13];
    const bf16* Wout = canon[14]; const bf16* bout = canon[15];
    const bf16* Wf1 = canon[16];  const bf16* bf1 = canon[17];
    const bf16* Wf2 = canon[18];  const bf16* bf2 = canon[19];
    const bf16* Wf3 = canon[20];  const bf16* bf3 = canon[21];

    // --- small persistent block (~28 MB) ---
    float* laneCbuf = (float*)carve(2 * sizeof(float));
    float* cbuf0 = (float*)carve((size_t)SD * HD * 4);
    float* cbuf1 = (float*)carve((size_t)SD * HD * 4);
    bf16* hbuf  = (bf16*)carve((size_t)SD * HD * 2);
    bf16* Wpack = (bf16*)carve((size_t)GD * (ED + HD) * 2);      // [2048,768]
    float* biasg = (float*)carve(GD * 4);
    float* be1f = (float*)carve(EHD * 4);
    float* be2f = (float*)carve(ED * 4);
    float* boutf = (float*)carve(OD * 4);
    float* bf1f = (float*)carve(F1D * 4);
    float* bf2f = (float*)carve(128 * 4);
    bf16* Wf2p  = (bf16*)carve((size_t)128 * ED * 2);
    bf16* out_o = (bf16*)carve((size_t)SD * OD * 2);
    bf16* xf1   = (bf16*)carve((size_t)SD * F1D * 2);
    bf16* xf2   = (bf16*)carve((size_t)SD * F2D * 2);

    const size_t SZ_X1 = (size_t)SD * TD * EHD * 2;   // 67 MB
    const size_t SZ_X2 = (size_t)SD * TD * ED * 2;    // 134 MB
    const size_t SZ_GATES = (size_t)SD * GD * 4;      // 33.5 MB

    const size_t used = (size_t)(wp - (char*)d_ws);
    const size_t remain = (ws_size > used) ? (ws_size - used) : 0;
    const bool persist = remain >= (SZ_X1 + SZ_X2 + 4096);

    bf16* x1 = nullptr; bf16* x2 = nullptr; float* gates = nullptr;
    bf16* x1t = nullptr; bf16* x2t = nullptr;
    if (persist) {
        char* r1 = (char*)carve(SZ_X1);    // 67 MB shared region
        x1 = (bf16*)r1;                    // live: embed GEMM1 -> GEMM2
        gates = (float*)r1;                // live: LSTM loop (disjoint lifetime)
        x2 = (bf16*)carve(SZ_X2);
    } else {
        gates = (float*)carve(SZ_GATES);
        x1t = (bf16*)carve((size_t)SD * EHD * 2);     // 1 MB per-step
        x2t = (bf16*)carve((size_t)SD * ED * 2);      // 2 MB per-step
    }

    const int NOSPLIT = 1 << 30;

    // dtype detect + canonicalize
    detect_kernel<<<1, 256, 0, stream>>>((const unsigned short*)d_in[0], dflag);
    for (int i = 0; i < 22; ++i)
        cvt_kernel<<<(nelem[i] + 255) / 256, 256, 0, stream>>>(d_in[i], canon[i], nelem[i], dflag);

    lane_kernel<<<1, 64, 0, stream>>>(lane, Wlg1, blg1, Wlg2, blg2, laneCbuf);
    zero_kernel<<<SD * HD / 256, 256, 0, stream>>>(cbuf0, hbuf);
    pack_w_kernel<<<GD * (ED + HD) / 256, 256, 0, stream>>>(Wih, Whh, Wpack);
    bias_g_kernel<<<GD / 256, 256, 0, stream>>>(bih, bhh, biasg);
    conv_bias_kernel<<<1, 256, 0, stream>>>(be1, be1f, EHD, EHD);
    conv_bias_kernel<<<1, 256, 0, stream>>>(be2, be2f, ED, ED);
    conv_bias_kernel<<<1, 256, 0, stream>>>(bout, boutf, OD, OD);
    conv_bias_kernel<<<1, 256, 0, stream>>>(bf1, bf1f, F1D, F1D);
    conv_bias_kernel<<<1, 256, 0, stream>>>(bf2, bf2f, F2D, 128);
    pad_wf2_kernel<<<128, 256, 0, stream>>>(Wf2, Wf2p);

    if (persist) {
        // Embedding layer 1: relu(laneC * (X @ We1^T) + be1), [262144,64]x[64,128]
        gemm_kernel<MODE_BF16><<<dim3(SD * TD / 128, 1), 256, 0, stream>>>(
            inputData, ID, nullptr, 0, NOSPLIT, We1, ID, be1f, laneCbuf, 1,
            x1, EHD, ID, EHD);
        // Embedding layer 2: relu(x1 @ We2^T + be2), scattered time-major into x2
        gemm_kernel<MODE_SCATTER><<<dim3(SD * TD / 128, ED / 128), 256, 0, stream>>>(
            x1, EHD, nullptr, 0, NOSPLIT, We2, EHD, be2f, nullptr, 1,
            x2, ED, EHD, ED);
    }

    // LSTM: 64 sequential steps
    for (int t = 0; t < TD; ++t) {
        const float* c_in = (t & 1) ? cbuf1 : cbuf0;
        float* c_out = (t & 1) ? cbuf0 : cbuf1;
        const bf16* xA;
        if (persist) {
            xA = x2 + (size_t)t * SD * ED;
        } else {
            // per-step embedding recompute: rows of x_t at stride T*I in inputData
            gemm_kernel<MODE_BF16><<<dim3(SD / 128, 1), 256, 0, stream>>>(
                inputData + (size_t)t * ID, TD * ID, nullptr, 0, NOSPLIT,
                We1, ID, be1f, laneCbuf, 1, x1t, EHD, ID, EHD);
            gemm_kernel<MODE_BF16><<<dim3(SD / 128, ED / 128), 256, 0, stream>>>(
                x1t, EHD, nullptr, 0, NOSPLIT, We2, EHD, be2f, nullptr, 1,
                x2t, ED, EHD, ED);
            xA = x2t;
        }
        gemm_kernel<MODE_F32><<<dim3(SD / 128, GD / 128), 256, 0, stream>>>(
            xA, ED, hbuf, HD, ED,
            Wpack, ED + HD, biasg, nullptr, 0, gates, GD, ED + HD, GD);
        gate_pool_kernel<<<SD * HD / 256, 256, 0, stream>>>(gates, c_in, c_out, hbuf);
    }
    // final c lives in cbuf0 (t=63: c_out = cbuf0)

    // Output head
    gemm_kernel<MODE_BF16><<<dim3(SD / 128, 1), 256, 0, stream>>>(
        hbuf, HD, nullptr, 0, NOSPLIT, Wout, HD, boutf, nullptr, 0,
        out_o, OD, HD, OD);
    gemm_kernel<MODE_BF16><<<dim3(SD / 128, F1D / 128), 256, 0, stream>>>(
        out_o, OD, nullptr, 0, NOSPLIT, Wf1, OD, bf1f, nullptr, 1,
        xf1, F1D, OD, F1D);
    gemm_kernel<MODE_BF16><<<dim3(SD / 128, 1), 256, 0, stream>>>(
        xf1, F1D, nullptr, 0, NOSPLIT, Wf2p, F1D, bf2f, nullptr, 1,
        xf2, F2D, F1D, F2D);
    f3_kernel<<<SD / 256, 256, 0, stream>>>(xf2, Wf3, bf3, laneCbuf, d_out, dflag);
    finalize_kernel<<<SD * HD / 256, 256, 0, stream>>>(hbuf, cbuf0, d_out, dflag);
}

// Round 4
// 2444.266 us; speedup vs baseline: 1.3295x; 1.3295x over previous
//
#include <hip/hip_runtime.h>
#include <hip/hip_bf16.h>
#include <cstdint>
#include <cstddef>

using bf16 = __hip_bfloat16;

typedef __attribute__((ext_vector_type(8))) short s8vec;    // 8 x bf16 (4 VGPRs) MFMA frag
typedef __attribute__((ext_vector_type(4))) float f4vec;    // 4 x fp32 accumulator

// Problem dims
#define SD 4096
#define TD 64
#define ID 64
#define EHD 128
#define ED 256
#define HD 512
#define GD 2048   // 4*H
#define OD 128
#define F1D 256
#define F2D 64

__device__ __forceinline__ float sigmf(float x) { return 1.0f / (1.0f + __expf(-x)); }
__device__ __forceinline__ float tanh_fast(float x) { return 1.0f - 2.0f / (__expf(2.0f * x) + 1.0f); }

__device__ __forceinline__ void async16(const bf16* g, void* lds) {
    __builtin_amdgcn_global_load_lds(
        (const __attribute__((address_space(1))) void*)g,
        (__attribute__((address_space(3))) void*)lds, 16, 0, 0);
}

// ---------------------------------------------------------------------------
// Generic NT GEMM: C[m,n] = act( scale * sum_k A[m,k]*B[n,k] + bias[n] )
// A split in K: rows come from A1 (k < ksplit, lda1) then A2 (lda2).
// B is [N,K] row-major bf16. M%128==0, K%64==0. grid = (M/128, N/128).
// 256 threads = 4 waves, each wave owns a 64x64 quadrant.  (m97 structure)
//
// MODE_LSTM: B is the gate-permuted Wpack — within each wave's 64-col span,
// ni (the 16-col MFMA block index) IS the gate index (i,f,g,o) of the same
// hidden j = (n0>>2) + wn*16 + lm. Epilogue computes the cell update in
// registers and writes c_out (fp32) + h_pre (bf16); no gates buffer.
// ---------------------------------------------------------------------------
constexpr int MODE_BF16 = 0;     // bf16 store at Cp[row*ldc+col], masked col<ncols
constexpr int MODE_SCATTER = 2;  // bf16 store, row r=(s*64+t) -> t*4096+s
constexpr int MODE_LSTM = 3;

template <int MODE>
__global__ __launch_bounds__(256, 2)
void gemm_kernel(const bf16* __restrict__ A1, int lda1,
                 const bf16* __restrict__ A2, int lda2, int ksplit,
                 const bf16* __restrict__ B, int ldb,
                 const float* __restrict__ bias,
                 const float* __restrict__ scale,
                 int relu, void* __restrict__ Cp, int ldc,
                 int K, int ncols,
                 const float* __restrict__ c_in, float* __restrict__ c_out,
                 bf16* __restrict__ h_pre)
{
    __shared__ __align__(16) bf16 As[128 * 64];
    __shared__ __align__(16) bf16 Bs[128 * 64];

    const int tid = threadIdx.x;
    const int lane = tid & 63;
    const int w = tid >> 6;
    const int wm = w & 1, wn = w >> 1;
    const int m0 = blockIdx.x * 128, n0 = blockIdx.y * 128;
    const int lm = lane & 15, lq = lane >> 4;

    f4vec acc[4][4];
#pragma unroll
    for (int i = 0; i < 4; ++i)
#pragma unroll
        for (int j = 0; j < 4; ++j) acc[i][j] = (f4vec){0.f, 0.f, 0.f, 0.f};

    for (int kc = 0; kc < K; kc += 64) {
        const bf16* Ab;
        int Alda, kk;
        if (kc < ksplit) { Ab = A1; Alda = lda1; kk = kc; }
        else             { Ab = A2; Alda = lda2; kk = kc - ksplit; }

        // Stage A and B tiles: 128 rows x 64 cols bf16 = 16KB each.
#pragma unroll
        for (int it = 0; it < 4; ++it) {
            int flat = it * 256 + tid;
            int row = flat >> 3, colu = flat & 7;
            const bf16* ga = Ab + (size_t)(m0 + row) * Alda + kk + colu * 8;
            const bf16* gb = B + (size_t)(n0 + row) * ldb + kc + colu * 8;
            uint32_t off = (uint32_t)(it * 256 + (tid & ~63)) * 16u;
            async16(ga, (char*)As + off);
            async16(gb, (char*)Bs + off);
        }
        __syncthreads();

#pragma unroll
        for (int ks = 0; ks < 64; ks += 32) {
            s8vec af[4], bfr[4];
#pragma unroll
            for (int mi = 0; mi < 4; ++mi)
                af[mi] = *(const s8vec*)(As + (wm * 64 + mi * 16 + lm) * 64 + ks + lq * 8);
#pragma unroll
            for (int ni = 0; ni < 4; ++ni)
                bfr[ni] = *(const s8vec*)(Bs + (wn * 64 + ni * 16 + lm) * 64 + ks + lq * 8);
#pragma unroll
            for (int mi = 0; mi < 4; ++mi)
#pragma unroll
                for (int ni = 0; ni < 4; ++ni)
                    acc[mi][ni] = __builtin_amdgcn_mfma_f32_16x16x32_bf16(af[mi], bfr[ni], acc[mi][ni], 0, 0, 0);
        }
        __syncthreads();
    }

    if constexpr (MODE == MODE_LSTM) {
        const int j = (n0 >> 2) + wn * 16 + lm;
        const float bi = bias[n0 + wn * 64 + lm];
        const float bff = bias[n0 + wn * 64 + 16 + lm];
        const float bg = bias[n0 + wn * 64 + 32 + lm];
        const float bo = bias[n0 + wn * 64 + 48 + lm];
#pragma unroll
        for (int mi = 0; mi < 4; ++mi) {
#pragma unroll
            for (int r = 0; r < 4; ++r) {
                const int row = m0 + wm * 64 + mi * 16 + lq * 4 + r;
                float gi = acc[mi][0][r] + bi;
                float gf = acc[mi][1][r] + bff;
                float gg = acc[mi][2][r] + bg;
                float go = acc[mi][3][r] + bo;
                float cn = sigmf(gf) * c_in[(size_t)row * HD + j] + sigmf(gi) * tanh_fast(gg);
                c_out[(size_t)row * HD + j] = cn;
                h_pre[(size_t)row * HD + j] = __float2bfloat16(sigmf(go) * tanh_fast(cn));
            }
        }
        return;
    }

    const float sc = scale ? scale[0] : 1.0f;
#pragma unroll
    for (int mi = 0; mi < 4; ++mi) {
#pragma unroll
        for (int ni = 0; ni < 4; ++ni) {
            const int gcol = n0 + wn * 64 + ni * 16 + lm;
            const float bv = bias[gcol];
#pragma unroll
            for (int r = 0; r < 4; ++r) {
                const int grow = m0 + wm * 64 + mi * 16 + lq * 4 + r;
                float v = acc[mi][ni][r] * sc + bv;
                if (relu) v = fmaxf(v, 0.f);
                if constexpr (MODE == MODE_BF16) {
                    if (gcol < ncols)
                        ((bf16*)Cp)[(size_t)grow * ldc + gcol] = __float2bfloat16(v);
                } else {  // MODE_SCATTER: row = s*64+t -> dest row t*4096+s
                    const int crow = (grow & 63) * SD + (grow >> 6);
                    ((bf16*)Cp)[(size_t)crow * ldc + gcol] = __float2bfloat16(v);
                }
            }
        }
    }
}

// ---------------------------------------------------------------------------
// Prep: one kernel for all weight conversions / packing (fp32 sources).
// Wpack permutation: output col p -> (tile=p>>7, q=p&127): wn=q>>6,
// gate=(q>>4)&3, lm=q&15; j=(p>>7)*32 + wn*16 + lm; orig row = gate*512+j.
// ---------------------------------------------------------------------------
__global__ void prep_kernel(const float* __restrict__ Wih, const float* __restrict__ Whh,
                            const float* __restrict__ bih, const float* __restrict__ bhh,
                            const float* __restrict__ We1, const float* __restrict__ We2,
                            const float* __restrict__ Wout, const float* __restrict__ Wf1,
                            const float* __restrict__ Wf2, const float* __restrict__ bf2,
                            bf16* __restrict__ Wpack, float* __restrict__ biasg,
                            bf16* __restrict__ We1b, bf16* __restrict__ We2b,
                            bf16* __restrict__ Woutb, bf16* __restrict__ Wf1b,
                            bf16* __restrict__ Wf2p, float* __restrict__ bf2f)
{
    int idx = blockIdx.x * 256 + threadIdx.x;
    const int S0 = GD * (ED + HD);          // 1572864
    if (idx < S0) {
        int p = idx / (ED + HD), k = idx - p * (ED + HD);
        int q = p & 127;
        int j = (p >> 7) * 32 + ((q >> 6) << 4) + (q & 15);
        int gate = (q >> 4) & 3;
        int orig = gate * HD + j;
        float v = (k < ED) ? Wih[(size_t)orig * ED + k] : Whh[(size_t)orig * HD + (k - ED)];
        Wpack[idx] = __float2bfloat16(v);
        return;
    }
    idx -= S0;
    if (idx < GD) {
        int p = idx, q = p & 127;
        int j = (p >> 7) * 32 + ((q >> 6) << 4) + (q & 15);
        int gate = (q >> 4) & 3;
        int orig = gate * HD + j;
        biasg[p] = bih[orig] + bhh[orig];
        return;
    }
    idx -= GD;
    if (idx < EHD * ID) { We1b[idx] = __float2bfloat16(We1[idx]); return; }
    idx -= EHD * ID;
    if (idx < ED * EHD) { We2b[idx] = __float2bfloat16(We2[idx]); return; }
    idx -= ED * EHD;
    if (idx < OD * HD) { Woutb[idx] = __float2bfloat16(Wout[idx]); return; }
    idx -= OD * HD;
    if (idx < F1D * OD) { Wf1b[idx] = __float2bfloat16(Wf1[idx]); return; }
    idx -= F1D * OD;
    if (idx < 128 * F1D) {
        int nrow = idx >> 8;
        Wf2p[idx] = (nrow < F2D) ? __float2bfloat16(Wf2[idx]) : __float2bfloat16(0.f);
        return;
    }
    idx -= 128 * F1D;
    if (idx < 128) { bf2f[idx] = (idx < F2D) ? bf2[idx] : 0.f; return; }
}

// vectorized fp32 -> bf16 for inputData (8 elems/thread)
__global__ void cvt_input_kernel(const float* __restrict__ src, bf16* __restrict__ dst)
{
    int i = (blockIdx.x * 256 + threadIdx.x) * 8;
    float4 a = *(const float4*)(src + i);
    float4 b = *(const float4*)(src + i + 4);
    bf16 o[8] = { __float2bfloat16(a.x), __float2bfloat16(a.y),
                  __float2bfloat16(a.z), __float2bfloat16(a.w),
                  __float2bfloat16(b.x), __float2bfloat16(b.y),
                  __float2bfloat16(b.z), __float2bfloat16(b.w) };
    *(uint4*)(dst + i) = *(const uint4*)o;
}

__global__ void lane_kernel(const float* __restrict__ lane, const float* __restrict__ Wlg1,
                            const float* __restrict__ blg1, const float* __restrict__ Wlg2,
                            const float* __restrict__ blg2, float* __restrict__ laneC)
{
    if (threadIdx.x != 0) return;
    const float l = lane[0];
    float acc = blg2[0];
    for (int k = 0; k < 32; ++k)
        acc += fmaxf(l * Wlg1[k] + blg1[k], 0.f) * Wlg2[k];
    float v = 1.f / (1.f + __expf(-acc));
    laneC[0] = v;
    laneC[1] = 1.f / v;
}

__global__ void zero_kernel(float* __restrict__ c0, bf16* __restrict__ h)
{
    int idx = blockIdx.x * 256 + threadIdx.x;
    if (idx < SD * HD) { c0[idx] = 0.f; h[idx] = __float2bfloat16(0.f); }
}

// spatial maxpool(3,1,-inf): hbuf[s,j] = max(h_pre[s-1..s+1, j]), 8 elems/thread
__global__ void maxpool_kernel(const bf16* __restrict__ hp, bf16* __restrict__ hout)
{
    int base = (blockIdx.x * 256 + threadIdx.x) * 8;   // < SD*HD
    int s = base >> 9;
    const uint4 vm = *(const uint4*)(hp + base);
    const unsigned short* m = (const unsigned short*)&vm;
    uint4 vu, vd;
    const unsigned short* u = nullptr; const unsigned short* d = nullptr;
    if (s > 0)      { vu = *(const uint4*)(hp + base - HD); u = (const unsigned short*)&vu; }
    if (s < SD - 1) { vd = *(const uint4*)(hp + base + HD); d = (const unsigned short*)&vd; }
    unsigned short o[8];
#pragma unroll
    for (int e = 0; e < 8; ++e) {
        float v = __bfloat162float(__ushort_as_bfloat16(m[e]));
        if (u) v = fmaxf(v, __bfloat162float(__ushort_as_bfloat16(u[e])));
        if (d) v = fmaxf(v, __bfloat162float(__ushort_as_bfloat16(d[e])));
        o[e] = __bfloat16_as_ushort(__float2bfloat16(v));
    }
    *(uint4*)(hout + base) = *(const uint4*)o;
}

__global__ void f3_kernel(const bf16* __restrict__ xf2, const float* __restrict__ Wf3,
                          const float* __restrict__ bf3, const float* __restrict__ laneC,
                          float* __restrict__ out)
{
    int s = blockIdx.x * 256 + threadIdx.x;
    if (s >= SD) return;
    float acc = bf3[0];
#pragma unroll
    for (int k = 0; k < F2D; ++k)
        acc += __bfloat162float(xf2[(size_t)s * F2D + k]) * Wf3[k];
    out[s] = acc * laneC[1];
}

__global__ void finalize_kernel(const bf16* __restrict__ h, const float* __restrict__ c,
                                float* __restrict__ out)
{
    int idx = blockIdx.x * 256 + threadIdx.x;
    if (idx >= SD * HD) return;
    out[SD + idx] = __bfloat162float(h[idx]);
    out[SD + SD * HD + idx] = c[idx];
}

// ---------------------------------------------------------------------------
extern "C" void kernel_launch(void* const* d_in, const int* in_sizes, int n_in,
                              void* d_out, int out_size, void* d_ws, size_t ws_size,
                              hipStream_t stream)
{
    (void)in_sizes; (void)n_in; (void)out_size;
    const float* inputDataF = (const float*)d_in[0];
    const float* lane = (const float*)d_in[1];
    const float* Wlg1 = (const float*)d_in[2];
    const float* blg1 = (const float*)d_in[3];
    const float* Wlg2 = (const float*)d_in[4];
    const float* blg2 = (const float*)d_in[5];
    const float* We1 = (const float*)d_in[6];
    const float* be1 = (const float*)d_in[7];
    const float* We2 = (const float*)d_in[8];
    const float* be2 = (const float*)d_in[9];
    const float* Wih = (const float*)d_in[10];
    const float* bih = (const float*)d_in[11];
    const float* Whh = (const float*)d_in[12];
    const float* bhh = (const float*)d_in[13];
    const float* Wout = (const float*)d_in[14];
    const float* bout = (const float*)d_in[15];
    const float* Wf1 = (const float*)d_in[16];
    const float* bf1 = (const float*)d_in[17];
    const float* Wf2 = (const float*)d_in[18];
    const float* bf2 = (const float*)d_in[19];
    const float* Wf3 = (const float*)d_in[20];
    const float* bf3 = (const float*)d_in[21];
    float* out = (float*)d_out;

    char* wp = (char*)d_ws;
    auto carve = [&](size_t bytes) { char* p = wp; wp += (bytes + 255) & ~(size_t)255; return p; };

    bf16* inb   = (bf16*)carve((size_t)SD * TD * ID * 2);        // 33.5 MB
    float* laneCbuf = (float*)carve(2 * sizeof(float));
    float* cbuf0 = (float*)carve((size_t)SD * HD * 4);
    float* cbuf1 = (float*)carve((size_t)SD * HD * 4);
    bf16* hbuf  = (bf16*)carve((size_t)SD * HD * 2);
    bf16* hpre  = (bf16*)carve((size_t)SD * HD * 2);
    bf16* Wpack = (bf16*)carve((size_t)GD * (ED + HD) * 2);      // 3.1 MB
    float* biasg = (float*)carve(GD * 4);
    float* bf2f = (float*)carve(128 * 4);
    bf16* We1b  = (bf16*)carve((size_t)EHD * ID * 2);
    bf16* We2b  = (bf16*)carve((size_t)ED * EHD * 2);
    bf16* Woutb = (bf16*)carve((size_t)OD * HD * 2);
    bf16* Wf1b  = (bf16*)carve((size_t)F1D * OD * 2);
    bf16* Wf2p  = (bf16*)carve((size_t)128 * F1D * 2);
    bf16* out_o = (bf16*)carve((size_t)SD * OD * 2);
    bf16* xf1   = (bf16*)carve((size_t)SD * F1D * 2);
    bf16* xf2   = (bf16*)carve((size_t)SD * F2D * 2);

    const size_t SZ_X1 = (size_t)SD * TD * EHD * 2;   // 67 MB
    const size_t SZ_X2 = (size_t)SD * TD * ED * 2;    // 134 MB
    const size_t used = (size_t)(wp - (char*)d_ws);
    const size_t remain = (ws_size > used) ? (ws_size - used) : 0;
    const bool persist = remain >= (SZ_X1 + SZ_X2 + 4096);

    bf16* x1 = nullptr; bf16* x2 = nullptr;
    bf16* x1t = nullptr; bf16* x2t = nullptr;
    if (persist) {
        x1 = (bf16*)carve(SZ_X1);
        x2 = (bf16*)carve(SZ_X2);
    } else {
        x1t = (bf16*)carve((size_t)SD * EHD * 2);
        x2t = (bf16*)carve((size_t)SD * ED * 2);
    }

    const int NOSPLIT = 1 << 30;
    const int PREP_N = GD * (ED + HD) + GD + EHD * ID + ED * EHD + OD * HD
                     + F1D * OD + 128 * F1D + 128;

    cvt_input_kernel<<<SD * TD * ID / (256 * 8), 256, 0, stream>>>(inputDataF, inb);
    prep_kernel<<<(PREP_N + 255) / 256, 256, 0, stream>>>(
        Wih, Whh, bih, bhh, We1, We2, Wout, Wf1, Wf2, bf2,
        Wpack, biasg, We1b, We2b, Woutb, Wf1b, Wf2p, bf2f);
    lane_kernel<<<1, 64, 0, stream>>>(lane, Wlg1, blg1, Wlg2, blg2, laneCbuf);
    zero_kernel<<<SD * HD / 256, 256, 0, stream>>>(cbuf0, hbuf);

    if (persist) {
        gemm_kernel<MODE_BF16><<<dim3(SD * TD / 128, 1), 256, 0, stream>>>(
            inb, ID, nullptr, 0, NOSPLIT, We1b, ID, be1, laneCbuf, 1,
            x1, EHD, ID, EHD, nullptr, nullptr, nullptr);
        gemm_kernel<MODE_SCATTER><<<dim3(SD * TD / 128, ED / 128), 256, 0, stream>>>(
            x1, EHD, nullptr, 0, NOSPLIT, We2b, EHD, be2, nullptr, 1,
            x2, ED, EHD, ED, nullptr, nullptr, nullptr);
    }

    // LSTM: 64 sequential steps
    for (int t = 0; t < TD; ++t) {
        const float* c_in = (t & 1) ? cbuf1 : cbuf0;
        float* c_out = (t & 1) ? cbuf0 : cbuf1;
        const bf16* xA;
        if (persist) {
            xA = x2 + (size_t)t * SD * ED;
        } else {
            gemm_kernel<MODE_BF16><<<dim3(SD / 128, 1), 256, 0, stream>>>(
                inb + (size_t)t * ID, TD * ID, nullptr, 0, NOSPLIT,
                We1b, ID, be1, laneCbuf, 1, x1t, EHD, ID, EHD,
                nullptr, nullptr, nullptr);
            gemm_kernel<MODE_BF16><<<dim3(SD / 128, ED / 128), 256, 0, stream>>>(
                x1t, EHD, nullptr, 0, NOSPLIT, We2b, EHD, be2, nullptr, 1,
                x2t, ED, EHD, ED, nullptr, nullptr, nullptr);
            xA = x2t;
        }
        gemm_kernel<MODE_LSTM><<<dim3(SD / 128, GD / 128), 256, 0, stream>>>(
            xA, ED, hbuf, HD, ED,
            Wpack, ED + HD, biasg, nullptr, 0, nullptr, 0, ED + HD, GD,
            c_in, c_out, hpre);
        maxpool_kernel<<<SD * HD / (256 * 8), 256, 0, stream>>>(hpre, hbuf);
    }
    // final c lives in cbuf0 (t=63: c_out = cbuf0)

    // Output head
    gemm_kernel<MODE_BF16><<<dim3(SD / 128, 1), 256, 0, stream>>>(
        hbuf, HD, nullptr, 0, NOSPLIT, Woutb, HD, bout, nullptr, 0,
        out_o, OD, HD, OD, nullptr, nullptr, nullptr);
    gemm_kernel<MODE_BF16><<<dim3(SD / 128, F1D / 128), 256, 0, stream>>>(
        out_o, OD, nullptr, 0, NOSPLIT, Wf1b, OD, bf1, nullptr, 1,
        xf1, F1D, OD, F1D, nullptr, nullptr, nullptr);
    gemm_kernel<MODE_BF16><<<dim3(SD / 128, 1), 256, 0, stream>>>(
        xf1, F1D, nullptr, 0, NOSPLIT, Wf2p, F1D, bf2f, nullptr, 1,
        xf2, F2D, F1D, F2D, nullptr, nullptr, nullptr);
    f3_kernel<<<SD / 256, 256, 0, stream>>>(xf2, Wf3, bf3, laneCbuf, out);
    finalize_kernel<<<SD * HD / 256, 256, 0, stream>>>(hbuf, cbuf0, out);
}